// Round 12
// baseline (287.059 us; speedup 1.0000x reference)
//
#include <hip/hip_runtime.h>

#define N_NODES 100000
#define IN_CH 64
#define HID 128
#define NBUCK ((N_NODES + 511) >> 9)   // 196 coarse buckets of 512 nodes
#define NCB 256                        // edge-chunk blocks for hist/bin

typedef short short8 __attribute__((ext_vector_type(8)));
typedef float floatx4 __attribute__((ext_vector_type(4)));
typedef float floatx2 __attribute__((ext_vector_type(2)));

__device__ __forceinline__ unsigned short f2bf(float f) {
    unsigned u = __builtin_bit_cast(unsigned, f);
    u += 0x7fffu + ((u >> 16) & 1u);  // RNE
    return (unsigned short)(u >> 16);
}

// ================= binned counting-sort CSR build (no global atomics) =================

__global__ __launch_bounds__(256) void scanb1_kernel(int* __restrict__ table,
                                                     int* __restrict__ tot) {
    __shared__ int s[NCB];
    int b = blockIdx.x, t = threadIdx.x;
    int c = table[b * NCB + t];
    s[t] = c;
    __syncthreads();
#pragma unroll
    for (int off = 1; off < NCB; off <<= 1) {
        int v = (t >= off) ? s[t - off] : 0;
        __syncthreads();
        s[t] += v;
        __syncthreads();
    }
    table[b * NCB + t] = s[t] - c;
    if (t == NCB - 1) tot[b] = s[t];
}

__global__ __launch_bounds__(256) void scanb2_kernel(const int* __restrict__ tot,
                                                     int* __restrict__ bstart,
                                                     int* __restrict__ ptr, int E) {
    __shared__ int s[256];
    int t = threadIdx.x;
    int v = (t < NBUCK) ? tot[t] : 0;
    s[t] = v;
    __syncthreads();
#pragma unroll
    for (int off = 1; off < 256; off <<= 1) {
        int u = (t >= off) ? s[t - off] : 0;
        __syncthreads();
        s[t] += u;
        __syncthreads();
    }
    if (t < NBUCK) bstart[t] = s[t] - v;
    if (t == 0) {
        bstart[NBUCK] = E;
        ptr[N_NODES] = E;
    }
}

__global__ __launch_bounds__(256) void bin_kernel(const int* __restrict__ src,
                                                  const int* __restrict__ dst,
                                                  const int* __restrict__ table,
                                                  const int* __restrict__ bstart,
                                                  unsigned* __restrict__ binned, int E, int chunk) {
    __shared__ int cur[NBUCK];
    int blk = blockIdx.x;
    for (int i = threadIdx.x; i < NBUCK; i += 256) cur[i] = bstart[i] + table[i * NCB + blk];
    __syncthreads();
    int e0 = blk * chunk;
    int e1 = min(E, e0 + chunk);
    for (int e = e0 + threadIdx.x; e < e1; e += 256) {
        int d = dst[e];
        int b = d >> 9;
        int pos = atomicAdd(&cur[b], 1);  // LDS atomic
        binned[pos] = (unsigned)src[e] | ((unsigned)(d & 511) << 17);
    }
}

__global__ __launch_bounds__(256) void place_kernel(const unsigned* __restrict__ binned,
                                                    const int* __restrict__ bstart,
                                                    int* __restrict__ ptr,
                                                    int* __restrict__ sorted, int N) {
    __shared__ int deg[512];
    __shared__ int cur[512];
    __shared__ int ssum[256];
    int b = blockIdx.x, t = threadIdx.x;
    int start = bstart[b], end = bstart[b + 1];
    deg[t] = 0;
    deg[t + 256] = 0;
    __syncthreads();
    for (int i = start + t; i < end; i += 256) atomicAdd(&deg[binned[i] >> 17], 1);
    __syncthreads();
    int a = deg[2 * t], c = deg[2 * t + 1];
    int s2 = a + c;
    ssum[t] = s2;
    __syncthreads();
#pragma unroll
    for (int off = 1; off < 256; off <<= 1) {
        int u = (t >= off) ? ssum[t - off] : 0;
        __syncthreads();
        ssum[t] += u;
        __syncthreads();
    }
    int excl2 = ssum[t] - s2;
    cur[2 * t] = excl2;
    cur[2 * t + 1] = excl2 + a;
    int n0 = b * 512 + 2 * t;
    if (n0 < N) ptr[n0] = start + excl2;
    if (n0 + 1 < N) ptr[n0 + 1] = start + excl2 + a;
    __syncthreads();
    for (int i = start + t; i < end; i += 256) {
        unsigned p = binned[i];
        int dl = p >> 17;
        int pos = start + atomicAdd(&cur[dl], 1);  // LDS atomic
        sorted[pos] = (int)(p & 0x1FFFF);
    }
}

// ========= fused hist + prep (bf16/fp8 converts of x + weight packs) =========
template <int K>
__device__ __forceinline__ void pack_dev(const float* __restrict__ Wn,
                                         const float* __restrict__ Ws,
                                         unsigned short* __restrict__ Bpack, int idx) {
    int s = idx >> 9;
    int rem = idx & 511;
    int t = rem >> 6;
    int lane = rem & 63;
    int quad = lane >> 4;
    int n = t * 16 + (lane & 15);
    unsigned short v[8];
#pragma unroll
    for (int j = 0; j < 8; ++j) {
        int k = s * 32 + quad * 8 + j;
        float w = (k < K) ? Wn[(size_t)k * HID + n] : Ws[(size_t)(k - K) * HID + n];
        v[j] = f2bf(w);
    }
    *(short8*)(Bpack + (size_t)idx * 8) = *(short8*)v;
}

// blocks [0,NCB): dst histogram; [NCB,NCB+8): pack0; [NCB+8,NCB+24): pack1; rest: x convert
__global__ __launch_bounds__(256) void histprep_kernel(const int* __restrict__ dst,
                                                       int* __restrict__ table, int E, int chunk,
                                                       const float* __restrict__ x,
                                                       unsigned short* __restrict__ x_bf,
                                                       unsigned char* __restrict__ x_f8,
                                                       const float* __restrict__ Wn0,
                                                       const float* __restrict__ Ws0,
                                                       unsigned short* __restrict__ Bpack0,
                                                       const float* __restrict__ Wn1,
                                                       const float* __restrict__ Ws1,
                                                       unsigned short* __restrict__ Bpack1,
                                                       int n4) {
    int b = blockIdx.x;
    if (b < NCB) {
        __shared__ int h[NBUCK];
        for (int i = threadIdx.x; i < NBUCK; i += 256) h[i] = 0;
        __syncthreads();
        int e0 = b * chunk;
        int e1 = min(E, e0 + chunk);
        for (int e = e0 + threadIdx.x; e < e1; e += 256) atomicAdd(&h[dst[e] >> 9], 1);
        __syncthreads();
        for (int i = threadIdx.x; i < NBUCK; i += 256) table[i * NCB + b] = h[i];
    } else if (b < NCB + 8) {
        pack_dev<IN_CH>(Wn0, Ws0, Bpack0, (b - NCB) * 256 + threadIdx.x);
    } else if (b < NCB + 24) {
        pack_dev<HID>(Wn1, Ws1, Bpack1, (b - NCB - 8) * 256 + threadIdx.x);
    } else {
        int i = (b - NCB - 24) * 256 + threadIdx.x;
        if (i < n4) {
            float4 v = ((const float4*)x)[i];
            ushort4 o;
            o.x = f2bf(v.x); o.y = f2bf(v.y); o.z = f2bf(v.z); o.w = f2bf(v.w);
            ((ushort4*)x_bf)[i] = o;
            int p8 = __builtin_amdgcn_cvt_pk_fp8_f32(v.x, v.y, 0, false);
            p8 = __builtin_amdgcn_cvt_pk_fp8_f32(v.z, v.w, p8, true);
            ((unsigned*)x_f8)[i] = (unsigned)p8;
        }
    }
}

// ===== per-node gather-mean (fp8 rows, fp32 accum) -> bf16 directly into LDS row =====
// Whole wave on one node: 16 lanes/row (NA dwords/lane), 4 edge slots, STEP=16.
// R9/R11-proven structure: UNCHECKED full blocks + one checked tail — no
// branches inside the load batch (that is what buys the memory-level parallelism).
template <int C>
__device__ __forceinline__ void gather_node_lds(const int* __restrict__ ptr,
                                                const int* __restrict__ srcs,
                                                const unsigned char* __restrict__ feat,
                                                int node, int N,
                                                unsigned short* __restrict__ lds_row,
                                                int lane) {
    constexpr int NA = C / 64;    // dwords per lane (1 for C=64, 2 for C=128)
    int g = lane >> 4;            // edge slot (0..3)
    int l = lane & 15;            // segment within row
    int nclamp = min(node, N - 1);
    int s0 = ptr[nclamp], s1 = ptr[nclamp + 1];
    int deg = s1 - s0;

    floatx2 acc2[2 * NA];
#pragma unroll
    for (int u = 0; u < 2 * NA; ++u) { acc2[u][0] = 0.0f; acc2[u][1] = 0.0f; }

    for (int jb = 0; jb < deg; jb += 64) {
        int rem = min(64, deg - jb);
        int idxreg = (jb + lane < deg) ? srcs[s0 + jb + lane] : 0;
        int fullend = rem & ~15;
        int o0 = 0;
        for (; o0 < fullend; o0 += 16) {     // unchecked full blocks
            uint v[4][NA];
#pragma unroll
            for (int q = 0; q < 4; ++q) {
                int idx = __shfl(idxreg, o0 + q * 4 + g);
                if (NA == 2) {
                    uint2 tt = *(const uint2*)(feat + (size_t)idx * C + l * 8);
                    v[q][0] = tt.x; v[q][1] = tt.y;
                } else {
                    v[q][0] = *(const unsigned*)(feat + (size_t)idx * C + l * 4);
                }
            }
#pragma unroll
            for (int q = 0; q < 4; ++q)
#pragma unroll
                for (int a = 0; a < NA; ++a) {
                    acc2[2 * a + 0] += __builtin_amdgcn_cvt_pk_f32_fp8(v[q][a], false);
                    acc2[2 * a + 1] += __builtin_amdgcn_cvt_pk_f32_fp8(v[q][a], true);
                }
        }
        if (o0 < rem) {                      // checked tail block
            uint v[4][NA];
#pragma unroll
            for (int q = 0; q < 4; ++q) {
                int o = o0 + q * 4 + g;
                int idx = __shfl(idxreg, o);
#pragma unroll
                for (int a = 0; a < NA; ++a) v[q][a] = 0;
                if (o < rem) {
                    if (NA == 2) {
                        uint2 tt = *(const uint2*)(feat + (size_t)idx * C + l * 8);
                        v[q][0] = tt.x; v[q][1] = tt.y;
                    } else {
                        v[q][0] = *(const unsigned*)(feat + (size_t)idx * C + l * 4);
                    }
                }
            }
#pragma unroll
            for (int q = 0; q < 4; ++q)
#pragma unroll
                for (int a = 0; a < NA; ++a) {
                    acc2[2 * a + 0] += __builtin_amdgcn_cvt_pk_f32_fp8(v[q][a], false);
                    acc2[2 * a + 1] += __builtin_amdgcn_cvt_pk_f32_fp8(v[q][a], true);
                }
        }
    }
    // reduce across the 4 edge-slots
#pragma unroll
    for (int m = 16; m < 64; m <<= 1) {
#pragma unroll
        for (int u = 0; u < 2 * NA; ++u) {
            acc2[u][0] += __shfl_xor(acc2[u][0], m, 64);
            acc2[u][1] += __shfl_xor(acc2[u][1], m, 64);
        }
    }
    if (g == 0) {
        float inv = (deg > 0) ? 1.0f / (float)deg : 0.0f;
        unsigned short o[4 * NA];
#pragma unroll
        for (int u = 0; u < 2 * NA; ++u) {
            o[2 * u + 0] = f2bf(acc2[u][0] * inv);
            o[2 * u + 1] = f2bf(acc2[u][1] * inv);
        }
        if (NA == 2) *(uint4*)(lds_row + l * 8) = *(const uint4*)o;
        else *(uint2*)(lds_row + l * 4) = *(const uint2*)o;
    }
}

// ================= fused SAGE layer: gather-mean -> LDS -> MFMA GEMM =================
// relu([mean|h] @ [Wn;Ws] + b); !FUSE_FC also emits fp8 copy for next aggregation.
template <int KT, bool FUSE_FC>
__global__ __launch_bounds__(256) void sage_fused(const int* __restrict__ ptr,
                                                  const int* __restrict__ srcs,
                                                  const unsigned char* __restrict__ feat8,
                                                  const unsigned short* __restrict__ hb,
                                                  const unsigned short* __restrict__ Bpack,
                                                  const float* __restrict__ bias,
                                                  const float* __restrict__ fcw,
                                                  const float* __restrict__ fcb,
                                                  unsigned short* __restrict__ outb,
                                                  unsigned char* __restrict__ out8,
                                                  float* __restrict__ outf, int N) {
    constexpr int KH = KT / 2;    // channels of this layer
    constexpr int LDA = KT + 8;
    __shared__ unsigned short As[64 * LDA];
    const int t = threadIdx.x;
    const int row0 = blockIdx.x * 64;
    const int lane = t & 63;
    const int wave = t >> 6;

    // stage self (h) half of each A row: As[r][KH .. KT)
    constexpr int HSEG = KH / 8;
    for (int c = t; c < 64 * HSEG; c += 256) {
        int r = c / HSEG, seg = c % HSEG;
        int rsrc = min(row0 + r, N - 1);
        *(uint4*)&As[r * LDA + KH + seg * 8] = *(const uint4*)(hb + (size_t)rsrc * KH + seg * 8);
    }

    // gather phase: wave w computes means for rows w*16 .. w*16+15 into As[r][0..KH)
    for (int i = 0; i < 16; ++i) {
        int r = wave * 16 + i;
        gather_node_lds<KH>(ptr, srcs, feat8, row0 + r, N, &As[r * LDA], lane);
    }
    __syncthreads();

    const int quad = lane >> 4;
    const int lo = lane & 15;

    floatx4 acc[8];
#pragma unroll
    for (int i = 0; i < 8; ++i)
#pragma unroll
        for (int r = 0; r < 4; ++r) acc[i][r] = 0.0f;

    const unsigned short* abase = &As[(wave * 16 + lo) * LDA + quad * 8];
#pragma unroll
    for (int s = 0; s < KT / 32; ++s) {
        short8 a = *(const short8*)(abase + s * 32);
        const short8* bp = (const short8*)Bpack + (size_t)(s * 8) * 64 + lane;
#pragma unroll
        for (int tt = 0; tt < 8; ++tt) {
            short8 b = bp[tt * 64];
            acc[tt] = __builtin_amdgcn_mfma_f32_16x16x32_bf16(a, b, acc[tt], 0, 0, 0);
        }
    }

    if (!FUSE_FC) {
#pragma unroll
        for (int tt = 0; tt < 8; ++tt) {
            int col = tt * 16 + lo;
            float bv = bias[col];
#pragma unroll
            for (int r = 0; r < 4; ++r) {
                int row = row0 + wave * 16 + quad * 4 + r;
                if (row < N) {
                    float v = fmaxf(acc[tt][r] + bv, 0.0f);
                    outb[(size_t)row * HID + col] = f2bf(v);
                    int p8 = __builtin_amdgcn_cvt_pk_fp8_f32(v, v, 0, false);
                    out8[(size_t)row * HID + col] = (unsigned char)(p8 & 0xff);
                }
            }
        }
    } else {
        float o0[4] = {}, o1[4] = {};
#pragma unroll
        for (int tt = 0; tt < 8; ++tt) {
            int col = tt * 16 + lo;
            float bv = bias[col];
            float w0 = fcw[col * 2 + 0];
            float w1 = fcw[col * 2 + 1];
#pragma unroll
            for (int r = 0; r < 4; ++r) {
                float v = fmaxf(acc[tt][r] + bv, 0.0f);
                o0[r] += v * w0;
                o1[r] += v * w1;
            }
        }
#pragma unroll
        for (int r = 0; r < 4; ++r) {
#pragma unroll
            for (int m = 8; m >= 1; m >>= 1) {
                o0[r] += __shfl_xor(o0[r], m, 16);
                o1[r] += __shfl_xor(o1[r], m, 16);
            }
        }
        if (lo == 0) {
#pragma unroll
            for (int r = 0; r < 4; ++r) {
                int row = row0 + wave * 16 + quad * 4 + r;
                if (row < N) {
                    outf[(size_t)row * 2 + 0] = o0[r] + fcb[0];
                    outf[(size_t)row * 2 + 1] = o1[r] + fcb[1];
                }
            }
        }
    }
}

extern "C" void kernel_launch(void* const* d_in, const int* in_sizes, int n_in,
                              void* d_out, int out_size, void* d_ws, size_t ws_size,
                              hipStream_t stream) {
    const float* x   = (const float*)d_in[0];
    const int*   ei  = (const int*)d_in[1];
    const float* Wn0 = (const float*)d_in[2];
    const float* Ws0 = (const float*)d_in[3];
    const float* b0  = (const float*)d_in[4];
    const float* Wn1 = (const float*)d_in[5];
    const float* Ws1 = (const float*)d_in[6];
    const float* b1  = (const float*)d_in[7];
    const float* fcw = (const float*)d_in[8];
    const float* fcb = (const float*)d_in[9];
    float* out = (float*)d_out;

    const int E = in_sizes[1] / 2;
    const int* src = ei;
    const int* dst = ei + E;
    const int N = N_NODES;
    const int chunk = (E + NCB - 1) / NCB;

    // workspace layout
    char* ws = (char*)d_ws;
    size_t off = 0;
    int* table  = (int*)(ws + off); off += (size_t)NBUCK * NCB * 4;
    int* tot    = (int*)(ws + off); off += 4096;
    int* bstart = (int*)(ws + off); off += 4096;
    int* ptr    = (int*)(ws + off); off += (size_t)(N + 1) * 4 + 60; off &= ~(size_t)63;
    unsigned* binned = (unsigned*)(ws + off); off += (size_t)E * 4;
    int* sorted = (int*)(ws + off); off += (size_t)E * 4;
    off = (off + 255) & ~(size_t)255;
    unsigned short* x_bf   = (unsigned short*)(ws + off); off += (size_t)N * IN_CH * 2;
    unsigned short* h1_bf  = (unsigned short*)(ws + off); off += (size_t)N * HID * 2;
    unsigned char*  h1_f8  = (unsigned char*)(ws + off);  off += (size_t)N * HID;
    unsigned char*  x_f8   = (unsigned char*)(ws + off);  off += (size_t)N * IN_CH;
    off = (off + 255) & ~(size_t)255;
    unsigned short* Bpack0 = (unsigned short*)(ws + off); off += (size_t)(2 * IN_CH / 32) * 8 * 64 * 8 * 2;
    unsigned short* Bpack1 = (unsigned short*)(ws + off); off += (size_t)(2 * HID / 32) * 8 * 64 * 8 * 2;

    // ---- CSR build + prep (fused hist/convert/pack) ----
    {
        int n4 = N * IN_CH / 4;
        int nblk = NCB + 24 + (n4 + 255) / 256;
        histprep_kernel<<<nblk, 256, 0, stream>>>(dst, table, E, chunk, x, x_bf, x_f8,
                                                  Wn0, Ws0, Bpack0, Wn1, Ws1, Bpack1, n4);
    }
    scanb1_kernel<<<NBUCK, 256, 0, stream>>>(table, tot);
    scanb2_kernel<<<1, 256, 0, stream>>>(tot, bstart, ptr, E);
    bin_kernel<<<NCB, 256, 0, stream>>>(src, dst, table, bstart, binned, E, chunk);
    place_kernel<<<NBUCK, 256, 0, stream>>>(binned, bstart, ptr, sorted, N);

    // ---- layer 0: fused gather(fp8 x) + GEMM -> h1 (bf16 + fp8) ----
    sage_fused<2 * IN_CH, false><<<(N + 63) / 64, 256, 0, stream>>>(
        ptr, sorted, x_f8, x_bf, Bpack0, b0, nullptr, nullptr, h1_bf, h1_f8, nullptr, N);

    // ---- layer 1: fused gather(fp8 h1) + GEMM + FC -> out ----
    sage_fused<2 * HID, true><<<(N + 63) / 64, 256, 0, stream>>>(
        ptr, sorted, h1_f8, h1_bf, Bpack1, b1, fcw, fcb, nullptr, nullptr, out, N);
}

// Round 13
// 274.981 us; speedup vs baseline: 1.0439x; 1.0439x over previous
//
#include <hip/hip_runtime.h>

#define N_NODES 100000
#define IN_CH 64
#define HID 128
#define NBUCK ((N_NODES + 511) >> 9)   // 196 coarse buckets of 512 nodes
#define NCB 256                        // edge-chunk blocks for hist/bin

typedef short short8 __attribute__((ext_vector_type(8)));
typedef float floatx4 __attribute__((ext_vector_type(4)));
typedef float floatx2 __attribute__((ext_vector_type(2)));

__device__ __forceinline__ unsigned short f2bf(float f) {
    unsigned u = __builtin_bit_cast(unsigned, f);
    u += 0x7fffu + ((u >> 16) & 1u);  // RNE
    return (unsigned short)(u >> 16);
}

// ========= fused hist + prep (bf16/fp8 converts of x + weight packs) =========
template <int K>
__device__ __forceinline__ void pack_dev(const float* __restrict__ Wn,
                                         const float* __restrict__ Ws,
                                         unsigned short* __restrict__ Bpack, int idx) {
    int s = idx >> 9;
    int rem = idx & 511;
    int t = rem >> 6;
    int lane = rem & 63;
    int quad = lane >> 4;
    int n = t * 16 + (lane & 15);
    unsigned short v[8];
#pragma unroll
    for (int j = 0; j < 8; ++j) {
        int k = s * 32 + quad * 8 + j;
        float w = (k < K) ? Wn[(size_t)k * HID + n] : Ws[(size_t)(k - K) * HID + n];
        v[j] = f2bf(w);
    }
    *(short8*)(Bpack + (size_t)idx * 8) = *(short8*)v;
}

// blocks [0,NCB): dst histogram; [NCB,NCB+8): pack0; [NCB+8,NCB+24): pack1; rest: x convert
__global__ __launch_bounds__(256) void histprep_kernel(const int* __restrict__ dst,
                                                       int* __restrict__ table, int E, int chunk,
                                                       const float* __restrict__ x,
                                                       unsigned short* __restrict__ x_bf,
                                                       unsigned char* __restrict__ x_f8,
                                                       const float* __restrict__ Wn0,
                                                       const float* __restrict__ Ws0,
                                                       unsigned short* __restrict__ Bpack0,
                                                       const float* __restrict__ Wn1,
                                                       const float* __restrict__ Ws1,
                                                       unsigned short* __restrict__ Bpack1,
                                                       int* __restrict__ scan_done, int n4) {
    int b = blockIdx.x;
    if (b < NCB) {
        if (b == 0 && threadIdx.x == 0) *scan_done = 0;  // init for scan12's last-block pattern
        __shared__ int h[NBUCK];
        for (int i = threadIdx.x; i < NBUCK; i += 256) h[i] = 0;
        __syncthreads();
        int e0 = b * chunk;
        int e1 = min(E, e0 + chunk);
        for (int e = e0 + threadIdx.x; e < e1; e += 256) atomicAdd(&h[dst[e] >> 9], 1);
        __syncthreads();
        for (int i = threadIdx.x; i < NBUCK; i += 256) table[i * NCB + b] = h[i];
    } else if (b < NCB + 8) {
        pack_dev<IN_CH>(Wn0, Ws0, Bpack0, (b - NCB) * 256 + threadIdx.x);
    } else if (b < NCB + 24) {
        pack_dev<HID>(Wn1, Ws1, Bpack1, (b - NCB - 8) * 256 + threadIdx.x);
    } else {
        int i = (b - NCB - 24) * 256 + threadIdx.x;
        if (i < n4) {
            float4 v = ((const float4*)x)[i];
            ushort4 o;
            o.x = f2bf(v.x); o.y = f2bf(v.y); o.z = f2bf(v.z); o.w = f2bf(v.w);
            ((ushort4*)x_bf)[i] = o;
            int p8 = __builtin_amdgcn_cvt_pk_fp8_f32(v.x, v.y, 0, false);
            p8 = __builtin_amdgcn_cvt_pk_fp8_f32(v.z, v.w, p8, true);
            ((unsigned*)x_f8)[i] = (unsigned)p8;
        }
    }
}

// ===== fused scan: per-bucket scan over block counts (scanb1) + last-done block
// ===== performs the bucket-start scan (scanb2). Device-scope atomics for tot.
__global__ __launch_bounds__(256) void scan12_kernel(int* __restrict__ table,
                                                     int* __restrict__ tot,
                                                     int* __restrict__ bstart,
                                                     int* __restrict__ ptr,
                                                     int* __restrict__ scan_done, int E) {
    __shared__ int s[NCB];
    __shared__ int lastflag;
    int b = blockIdx.x, t = threadIdx.x;
    int c = table[b * NCB + t];
    s[t] = c;
    __syncthreads();
#pragma unroll
    for (int off = 1; off < NCB; off <<= 1) {
        int v = (t >= off) ? s[t - off] : 0;
        __syncthreads();
        s[t] += v;
        __syncthreads();
    }
    table[b * NCB + t] = s[t] - c;
    if (t == NCB - 1) {
        __hip_atomic_store(&tot[b], s[t], __ATOMIC_RELAXED, __HIP_MEMORY_SCOPE_AGENT);
        int prev = __hip_atomic_fetch_add(scan_done, 1, __ATOMIC_ACQ_REL, __HIP_MEMORY_SCOPE_AGENT);
        lastflag = (prev == NBUCK - 1);
    }
    __syncthreads();
    if (!lastflag) return;
    // this block is the last to finish scanb1 — do scanb2 (bucket-start scan)
    int v = (t < NBUCK) ? __hip_atomic_load(&tot[t], __ATOMIC_RELAXED, __HIP_MEMORY_SCOPE_AGENT) : 0;
    s[t] = v;
    __syncthreads();
#pragma unroll
    for (int off = 1; off < 256; off <<= 1) {
        int u = (t >= off) ? s[t - off] : 0;
        __syncthreads();
        s[t] += u;
        __syncthreads();
    }
    if (t < NBUCK) bstart[t] = s[t] - v;
    if (t == 0) {
        bstart[NBUCK] = E;
        ptr[N_NODES] = E;
    }
}

__global__ __launch_bounds__(256) void bin_kernel(const int* __restrict__ src,
                                                  const int* __restrict__ dst,
                                                  const int* __restrict__ table,
                                                  const int* __restrict__ bstart,
                                                  unsigned* __restrict__ binned, int E, int chunk) {
    __shared__ int cur[NBUCK];
    int blk = blockIdx.x;
    for (int i = threadIdx.x; i < NBUCK; i += 256) cur[i] = bstart[i] + table[i * NCB + blk];
    __syncthreads();
    int e0 = blk * chunk;
    int e1 = min(E, e0 + chunk);
    for (int e = e0 + threadIdx.x; e < e1; e += 256) {
        int d = dst[e];
        int b = d >> 9;
        int pos = atomicAdd(&cur[b], 1);  // LDS atomic
        binned[pos] = (unsigned)src[e] | ((unsigned)(d & 511) << 17);
    }
}

__global__ __launch_bounds__(256) void place_kernel(const unsigned* __restrict__ binned,
                                                    const int* __restrict__ bstart,
                                                    int* __restrict__ ptr,
                                                    int* __restrict__ sorted, int N) {
    __shared__ int deg[512];
    __shared__ int cur[512];
    __shared__ int ssum[256];
    int b = blockIdx.x, t = threadIdx.x;
    int start = bstart[b], end = bstart[b + 1];
    deg[t] = 0;
    deg[t + 256] = 0;
    __syncthreads();
    for (int i = start + t; i < end; i += 256) atomicAdd(&deg[binned[i] >> 17], 1);
    __syncthreads();
    int a = deg[2 * t], c = deg[2 * t + 1];
    int s2 = a + c;
    ssum[t] = s2;
    __syncthreads();
#pragma unroll
    for (int off = 1; off < 256; off <<= 1) {
        int u = (t >= off) ? ssum[t - off] : 0;
        __syncthreads();
        ssum[t] += u;
        __syncthreads();
    }
    int excl2 = ssum[t] - s2;
    cur[2 * t] = excl2;
    cur[2 * t + 1] = excl2 + a;
    int n0 = b * 512 + 2 * t;
    if (n0 < N) ptr[n0] = start + excl2;
    if (n0 + 1 < N) ptr[n0 + 1] = start + excl2 + a;
    __syncthreads();
    for (int i = start + t; i < end; i += 256) {
        unsigned p = binned[i];
        int dl = p >> 17;
        int pos = start + atomicAdd(&cur[dl], 1);  // LDS atomic
        sorted[pos] = (int)(p & 0x1FFFF);
    }
}

// ================= gather + mean (fp8 rows, fp32 accumulate, bf16 out) =================
// 16 lanes/row, NA = C/64 dwords/lane; G = 4 edges/slot, STEP = 16 — matches
// deg~Poisson(16). UNCHECKED full blocks + one checked tail; no branches inside
// the load batch (R10 lesson: branching there destroys memory-level parallelism).
template <int C>
__global__ __launch_bounds__(256) void gather_mean_f8(const int* __restrict__ ptr,
                                                      const int* __restrict__ srcs,
                                                      const unsigned char* __restrict__ feat,
                                                      unsigned short* __restrict__ mean, int N) {
    constexpr int NA = C / 64;    // dwords per lane (1 for C=64, 2 for C=128)
    int w = (blockIdx.x * blockDim.x + threadIdx.x) >> 6;
    if (w >= N) return;
    int lane = threadIdx.x & 63;
    int g = lane >> 4;            // edge slot within group (0..3)
    int l = lane & 15;            // segment within row
    int s0 = ptr[w], s1 = ptr[w + 1];
    int deg = s1 - s0;

    floatx2 acc2[2 * NA];
#pragma unroll
    for (int u = 0; u < 2 * NA; ++u) { acc2[u][0] = 0.0f; acc2[u][1] = 0.0f; }

    for (int jb = 0; jb < deg; jb += 64) {
        int rem = min(64, deg - jb);
        int idxreg = (jb + lane < deg) ? srcs[s0 + jb + lane] : 0;
        int fullend = rem & ~15;
        int o0 = 0;
        for (; o0 < fullend; o0 += 16) {     // unchecked full blocks
            uint v[4][NA];
#pragma unroll
            for (int q = 0; q < 4; ++q) {
                int idx = __shfl(idxreg, o0 + q * 4 + g);
                if (NA == 2) {
                    uint2 tt = *(const uint2*)(feat + (size_t)idx * C + l * 8);
                    v[q][0] = tt.x; v[q][1] = tt.y;
                } else {
                    v[q][0] = *(const unsigned*)(feat + (size_t)idx * C + l * 4);
                }
            }
#pragma unroll
            for (int q = 0; q < 4; ++q)
#pragma unroll
                for (int a = 0; a < NA; ++a) {
                    acc2[2 * a + 0] += __builtin_amdgcn_cvt_pk_f32_fp8(v[q][a], false);
                    acc2[2 * a + 1] += __builtin_amdgcn_cvt_pk_f32_fp8(v[q][a], true);
                }
        }
        if (o0 < rem) {                      // checked tail block
            uint v[4][NA];
#pragma unroll
            for (int q = 0; q < 4; ++q) {
                int o = o0 + q * 4 + g;
                int idx = __shfl(idxreg, o);
#pragma unroll
                for (int a = 0; a < NA; ++a) v[q][a] = 0;
                if (o < rem) {
                    if (NA == 2) {
                        uint2 tt = *(const uint2*)(feat + (size_t)idx * C + l * 8);
                        v[q][0] = tt.x; v[q][1] = tt.y;
                    } else {
                        v[q][0] = *(const unsigned*)(feat + (size_t)idx * C + l * 4);
                    }
                }
            }
#pragma unroll
            for (int q = 0; q < 4; ++q)
#pragma unroll
                for (int a = 0; a < NA; ++a) {
                    acc2[2 * a + 0] += __builtin_amdgcn_cvt_pk_f32_fp8(v[q][a], false);
                    acc2[2 * a + 1] += __builtin_amdgcn_cvt_pk_f32_fp8(v[q][a], true);
                }
        }
    }
    // reduce across the 4 edge-slots (lanes differing in bits >= 4)
#pragma unroll
    for (int m = 16; m < 64; m <<= 1) {
#pragma unroll
        for (int u = 0; u < 2 * NA; ++u) {
            acc2[u][0] += __shfl_xor(acc2[u][0], m, 64);
            acc2[u][1] += __shfl_xor(acc2[u][1], m, 64);
        }
    }
    if (g == 0) {
        float inv = (deg > 0) ? 1.0f / (float)deg : 0.0f;
        unsigned short o[4 * NA];
#pragma unroll
        for (int u = 0; u < 2 * NA; ++u) {
            o[2 * u + 0] = f2bf(acc2[u][0] * inv);
            o[2 * u + 1] = f2bf(acc2[u][1] * inv);
        }
        if (NA == 2) *(uint4*)(mean + (size_t)w * C + l * 8) = *(const uint4*)o;
        else *(uint2*)(mean + (size_t)w * C + l * 4) = *(const uint2*)o;
    }
}

// ================= MFMA SAGE GEMM: relu([mean|h] @ [Wn;Ws] + b) =================
// !FUSE_FC also emits an fp8(e4m3) copy of the output for the next aggregation.
template <int KT, bool FUSE_FC>
__global__ __launch_bounds__(256) void sage_gemm_mfma(const unsigned short* __restrict__ meanb,
                                                      const unsigned short* __restrict__ hb,
                                                      const unsigned short* __restrict__ Bpack,
                                                      const float* __restrict__ bias,
                                                      const float* __restrict__ fcw,
                                                      const float* __restrict__ fcb,
                                                      unsigned short* __restrict__ outb,
                                                      unsigned char* __restrict__ out8,
                                                      float* __restrict__ outf, int N) {
    constexpr int KH = KT / 2;
    constexpr int LDA = KT + 8;
    __shared__ unsigned short As[64 * LDA];
    const int t = threadIdx.x;
    const int row0 = blockIdx.x * 64;

    constexpr int SEGS = KT / 8;
    for (int c = t; c < 64 * SEGS; c += 256) {
        int r = c / SEGS, seg = c % SEGS;
        int rsrc = row0 + r;
        if (rsrc >= N) rsrc = N - 1;
        const unsigned short* srcp = (seg < SEGS / 2)
                                         ? meanb + (size_t)rsrc * KH + seg * 8
                                         : hb + (size_t)rsrc * KH + (seg - SEGS / 2) * 8;
        *(uint4*)&As[r * LDA + seg * 8] = *(const uint4*)srcp;
    }
    __syncthreads();

    const int lane = t & 63;
    const int wave = t >> 6;
    const int quad = lane >> 4;
    const int lo = lane & 15;

    floatx4 acc[8];
#pragma unroll
    for (int i = 0; i < 8; ++i)
#pragma unroll
        for (int r = 0; r < 4; ++r) acc[i][r] = 0.0f;

    const unsigned short* abase = &As[(wave * 16 + lo) * LDA + quad * 8];
#pragma unroll
    for (int s = 0; s < KT / 32; ++s) {
        short8 a = *(const short8*)(abase + s * 32);
        const short8* bp = (const short8*)Bpack + (size_t)(s * 8) * 64 + lane;
#pragma unroll
        for (int tt = 0; tt < 8; ++tt) {
            short8 b = bp[tt * 64];
            acc[tt] = __builtin_amdgcn_mfma_f32_16x16x32_bf16(a, b, acc[tt], 0, 0, 0);
        }
    }

    if (!FUSE_FC) {
#pragma unroll
        for (int tt = 0; tt < 8; ++tt) {
            int col = tt * 16 + lo;
            float bv = bias[col];
#pragma unroll
            for (int r = 0; r < 4; ++r) {
                int row = row0 + wave * 16 + quad * 4 + r;
                if (row < N) {
                    float v = fmaxf(acc[tt][r] + bv, 0.0f);
                    outb[(size_t)row * HID + col] = f2bf(v);
                    int p8 = __builtin_amdgcn_cvt_pk_fp8_f32(v, v, 0, false);
                    out8[(size_t)row * HID + col] = (unsigned char)(p8 & 0xff);
                }
            }
        }
    } else {
        float o0[4] = {}, o1[4] = {};
#pragma unroll
        for (int tt = 0; tt < 8; ++tt) {
            int col = tt * 16 + lo;
            float bv = bias[col];
            float w0 = fcw[col * 2 + 0];
            float w1 = fcw[col * 2 + 1];
#pragma unroll
            for (int r = 0; r < 4; ++r) {
                float v = fmaxf(acc[tt][r] + bv, 0.0f);
                o0[r] += v * w0;
                o1[r] += v * w1;
            }
        }
#pragma unroll
        for (int r = 0; r < 4; ++r) {
#pragma unroll
            for (int m = 8; m >= 1; m >>= 1) {
                o0[r] += __shfl_xor(o0[r], m, 16);
                o1[r] += __shfl_xor(o1[r], m, 16);
            }
        }
        if (lo == 0) {
#pragma unroll
            for (int r = 0; r < 4; ++r) {
                int row = row0 + wave * 16 + quad * 4 + r;
                if (row < N) {
                    outf[(size_t)row * 2 + 0] = o0[r] + fcb[0];
                    outf[(size_t)row * 2 + 1] = o1[r] + fcb[1];
                }
            }
        }
    }
}

extern "C" void kernel_launch(void* const* d_in, const int* in_sizes, int n_in,
                              void* d_out, int out_size, void* d_ws, size_t ws_size,
                              hipStream_t stream) {
    const float* x   = (const float*)d_in[0];
    const int*   ei  = (const int*)d_in[1];
    const float* Wn0 = (const float*)d_in[2];
    const float* Ws0 = (const float*)d_in[3];
    const float* b0  = (const float*)d_in[4];
    const float* Wn1 = (const float*)d_in[5];
    const float* Ws1 = (const float*)d_in[6];
    const float* b1  = (const float*)d_in[7];
    const float* fcw = (const float*)d_in[8];
    const float* fcb = (const float*)d_in[9];
    float* out = (float*)d_out;

    const int E = in_sizes[1] / 2;
    const int* src = ei;
    const int* dst = ei + E;
    const int N = N_NODES;
    const int chunk = (E + NCB - 1) / NCB;

    // workspace layout
    char* ws = (char*)d_ws;
    size_t off = 0;
    int* table  = (int*)(ws + off); off += (size_t)NBUCK * NCB * 4;
    int* tot    = (int*)(ws + off); off += 4096;
    int* bstart = (int*)(ws + off); off += 4096;
    int* scan_done = (int*)(ws + off); off += 256;
    int* ptr    = (int*)(ws + off); off += (size_t)(N + 1) * 4 + 60; off &= ~(size_t)63;
    unsigned* binned = (unsigned*)(ws + off); off += (size_t)E * 4;
    int* sorted = (int*)(ws + off); off += (size_t)E * 4;
    off = (off + 255) & ~(size_t)255;
    unsigned short* x_bf   = (unsigned short*)(ws + off); off += (size_t)N * IN_CH * 2;
    unsigned short* mean0  = (unsigned short*)(ws + off); off += (size_t)N * IN_CH * 2;
    unsigned short* h1_bf  = (unsigned short*)(ws + off); off += (size_t)N * HID * 2;
    unsigned short* mean1  = (unsigned short*)(ws + off); off += (size_t)N * HID * 2;
    unsigned char*  h1_f8  = (unsigned char*)(ws + off);  off += (size_t)N * HID;
    unsigned char*  x_f8   = (unsigned char*)(ws + off);  off += (size_t)N * IN_CH;
    off = (off + 255) & ~(size_t)255;
    unsigned short* Bpack0 = (unsigned short*)(ws + off); off += (size_t)(2 * IN_CH / 32) * 8 * 64 * 8 * 2;
    unsigned short* Bpack1 = (unsigned short*)(ws + off); off += (size_t)(2 * HID / 32) * 8 * 64 * 8 * 2;

    // ---- CSR build + prep (8 launches total this call) ----
    {
        int n4 = N * IN_CH / 4;
        int nblk = NCB + 24 + (n4 + 255) / 256;
        histprep_kernel<<<nblk, 256, 0, stream>>>(dst, table, E, chunk, x, x_bf, x_f8,
                                                  Wn0, Ws0, Bpack0, Wn1, Ws1, Bpack1,
                                                  scan_done, n4);
    }
    scan12_kernel<<<NBUCK, 256, 0, stream>>>(table, tot, bstart, ptr, scan_done, E);
    bin_kernel<<<NCB, 256, 0, stream>>>(src, dst, table, bstart, binned, E, chunk);
    place_kernel<<<NBUCK, 256, 0, stream>>>(binned, bstart, ptr, sorted, N);

    // ---- layer 0 (fp8 aggregation) ----
    gather_mean_f8<IN_CH><<<(N * 64 + 255) / 256, 256, 0, stream>>>(ptr, sorted, x_f8, mean0, N);
    sage_gemm_mfma<2 * IN_CH, false><<<(N + 63) / 64, 256, 0, stream>>>(
        mean0, x_bf, Bpack0, b0, nullptr, nullptr, h1_bf, h1_f8, nullptr, N);

    // ---- layer 1 (fp8 aggregation) + fused fc ----
    gather_mean_f8<HID><<<(N * 64 + 255) / 256, 256, 0, stream>>>(ptr, sorted, h1_f8, mean1, N);
    sage_gemm_mfma<2 * HID, true><<<(N + 63) / 64, 256, 0, stream>>>(
        mean1, h1_bf, Bpack1, b1, fcw, fcb, nullptr, nullptr, out, N);
}

// Round 14
// 253.875 us; speedup vs baseline: 1.1307x; 1.0831x over previous
//
#include <hip/hip_runtime.h>

#define N_NODES 100000
#define IN_CH 64
#define HID 128
#define NBUCK ((N_NODES + 511) >> 9)   // 196 coarse buckets of 512 nodes
#define NCB 256                        // edge-chunk blocks for hist/bin

typedef short short8 __attribute__((ext_vector_type(8)));
typedef float floatx4 __attribute__((ext_vector_type(4)));
typedef float floatx2 __attribute__((ext_vector_type(2)));

__device__ __forceinline__ unsigned short f2bf(float f) {
    unsigned u = __builtin_bit_cast(unsigned, f);
    u += 0x7fffu + ((u >> 16) & 1u);  // RNE
    return (unsigned short)(u >> 16);
}

// ========= fused hist + prep (bf16/fp8 converts of x + weight packs) =========
template <int K>
__device__ __forceinline__ void pack_dev(const float* __restrict__ Wn,
                                         const float* __restrict__ Ws,
                                         unsigned short* __restrict__ Bpack, int idx) {
    int s = idx >> 9;
    int rem = idx & 511;
    int t = rem >> 6;
    int lane = rem & 63;
    int quad = lane >> 4;
    int n = t * 16 + (lane & 15);
    unsigned short v[8];
#pragma unroll
    for (int j = 0; j < 8; ++j) {
        int k = s * 32 + quad * 8 + j;
        float w = (k < K) ? Wn[(size_t)k * HID + n] : Ws[(size_t)(k - K) * HID + n];
        v[j] = f2bf(w);
    }
    *(short8*)(Bpack + (size_t)idx * 8) = *(short8*)v;
}

// blocks [0,NCB): dst histogram; [NCB,NCB+8): pack0; [NCB+8,NCB+24): pack1; rest: x convert
__global__ __launch_bounds__(256) void histprep_kernel(const int* __restrict__ dst,
                                                       int* __restrict__ table, int E, int chunk,
                                                       const float* __restrict__ x,
                                                       unsigned short* __restrict__ x_bf,
                                                       unsigned char* __restrict__ x_f8,
                                                       const float* __restrict__ Wn0,
                                                       const float* __restrict__ Ws0,
                                                       unsigned short* __restrict__ Bpack0,
                                                       const float* __restrict__ Wn1,
                                                       const float* __restrict__ Ws1,
                                                       unsigned short* __restrict__ Bpack1,
                                                       int* __restrict__ scan_done, int n4) {
    int b = blockIdx.x;
    if (b < NCB) {
        if (b == 0 && threadIdx.x == 0) *scan_done = 0;  // init for scan12's last-block pattern
        __shared__ int h[NBUCK];
        for (int i = threadIdx.x; i < NBUCK; i += 256) h[i] = 0;
        __syncthreads();
        int e0 = b * chunk;
        int e1 = min(E, e0 + chunk);
        for (int e = e0 + threadIdx.x; e < e1; e += 256) atomicAdd(&h[dst[e] >> 9], 1);
        __syncthreads();
        for (int i = threadIdx.x; i < NBUCK; i += 256) table[i * NCB + b] = h[i];
    } else if (b < NCB + 8) {
        pack_dev<IN_CH>(Wn0, Ws0, Bpack0, (b - NCB) * 256 + threadIdx.x);
    } else if (b < NCB + 24) {
        pack_dev<HID>(Wn1, Ws1, Bpack1, (b - NCB - 8) * 256 + threadIdx.x);
    } else {
        int i = (b - NCB - 24) * 256 + threadIdx.x;
        if (i < n4) {
            float4 v = ((const float4*)x)[i];
            ushort4 o;
            o.x = f2bf(v.x); o.y = f2bf(v.y); o.z = f2bf(v.z); o.w = f2bf(v.w);
            ((ushort4*)x_bf)[i] = o;
            int p8 = __builtin_amdgcn_cvt_pk_fp8_f32(v.x, v.y, 0, false);
            p8 = __builtin_amdgcn_cvt_pk_fp8_f32(v.z, v.w, p8, true);
            ((unsigned*)x_f8)[i] = (unsigned)p8;
        }
    }
}

// ===== fused scan: per-bucket scan over block counts (scanb1) + last-done block
// ===== performs the bucket-start scan (scanb2). Device-scope atomics for tot.
__global__ __launch_bounds__(256) void scan12_kernel(int* __restrict__ table,
                                                     int* __restrict__ tot,
                                                     int* __restrict__ bstart,
                                                     int* __restrict__ ptr,
                                                     int* __restrict__ scan_done, int E) {
    __shared__ int s[NCB];
    __shared__ int lastflag;
    int b = blockIdx.x, t = threadIdx.x;
    int c = table[b * NCB + t];
    s[t] = c;
    __syncthreads();
#pragma unroll
    for (int off = 1; off < NCB; off <<= 1) {
        int v = (t >= off) ? s[t - off] : 0;
        __syncthreads();
        s[t] += v;
        __syncthreads();
    }
    table[b * NCB + t] = s[t] - c;
    if (t == NCB - 1) {
        __hip_atomic_store(&tot[b], s[t], __ATOMIC_RELAXED, __HIP_MEMORY_SCOPE_AGENT);
        int prev = __hip_atomic_fetch_add(scan_done, 1, __ATOMIC_ACQ_REL, __HIP_MEMORY_SCOPE_AGENT);
        lastflag = (prev == NBUCK - 1);
    }
    __syncthreads();
    if (!lastflag) return;
    // this block is the last to finish scanb1 — do scanb2 (bucket-start scan)
    int v = (t < NBUCK) ? __hip_atomic_load(&tot[t], __ATOMIC_RELAXED, __HIP_MEMORY_SCOPE_AGENT) : 0;
    s[t] = v;
    __syncthreads();
#pragma unroll
    for (int off = 1; off < 256; off <<= 1) {
        int u = (t >= off) ? s[t - off] : 0;
        __syncthreads();
        s[t] += u;
        __syncthreads();
    }
    if (t < NBUCK) bstart[t] = s[t] - v;
    if (t == 0) {
        bstart[NBUCK] = E;
        ptr[N_NODES] = E;
    }
}

__global__ __launch_bounds__(256) void bin_kernel(const int* __restrict__ src,
                                                  const int* __restrict__ dst,
                                                  const int* __restrict__ table,
                                                  const int* __restrict__ bstart,
                                                  unsigned* __restrict__ binned, int E, int chunk) {
    __shared__ int cur[NBUCK];
    int blk = blockIdx.x;
    for (int i = threadIdx.x; i < NBUCK; i += 256) cur[i] = bstart[i] + table[i * NCB + blk];
    __syncthreads();
    int e0 = blk * chunk;
    int e1 = min(E, e0 + chunk);
    for (int e = e0 + threadIdx.x; e < e1; e += 256) {
        int d = dst[e];
        int b = d >> 9;
        int pos = atomicAdd(&cur[b], 1);  // LDS atomic
        binned[pos] = (unsigned)src[e] | ((unsigned)(d & 511) << 17);
    }
}

__global__ __launch_bounds__(256) void place_kernel(const unsigned* __restrict__ binned,
                                                    const int* __restrict__ bstart,
                                                    int* __restrict__ ptr,
                                                    int* __restrict__ sorted, int N) {
    __shared__ int deg[512];
    __shared__ int cur[512];
    __shared__ int ssum[256];
    int b = blockIdx.x, t = threadIdx.x;
    int start = bstart[b], end = bstart[b + 1];
    deg[t] = 0;
    deg[t + 256] = 0;
    __syncthreads();
    for (int i = start + t; i < end; i += 256) atomicAdd(&deg[binned[i] >> 17], 1);
    __syncthreads();
    int a = deg[2 * t], c = deg[2 * t + 1];
    int s2 = a + c;
    ssum[t] = s2;
    __syncthreads();
#pragma unroll
    for (int off = 1; off < 256; off <<= 1) {
        int u = (t >= off) ? ssum[t - off] : 0;
        __syncthreads();
        ssum[t] += u;
        __syncthreads();
    }
    int excl2 = ssum[t] - s2;
    cur[2 * t] = excl2;
    cur[2 * t + 1] = excl2 + a;
    int n0 = b * 512 + 2 * t;
    if (n0 < N) ptr[n0] = start + excl2;
    if (n0 + 1 < N) ptr[n0 + 1] = start + excl2 + a;
    __syncthreads();
    for (int i = start + t; i < end; i += 256) {
        unsigned p = binned[i];
        int dl = p >> 17;
        int pos = start + atomicAdd(&cur[dl], 1);  // LDS atomic
        sorted[pos] = (int)(p & 0x1FFFF);
    }
}

// ================= gather + mean (fp8 rows, fp32 accumulate, bf16 out) =================
// 16 lanes/row, NA = C/64 dwords/lane; G = 4 edges/slot, STEP = 16 — matches
// deg~Poisson(16). UNCHECKED full blocks + one checked tail; no branches inside
// the load batch (R10 lesson: branching there destroys memory-level parallelism).
template <int C>
__global__ __launch_bounds__(256) void gather_mean_f8(const int* __restrict__ ptr,
                                                      const int* __restrict__ srcs,
                                                      const unsigned char* __restrict__ feat,
                                                      unsigned short* __restrict__ mean, int N) {
    constexpr int NA = C / 64;    // dwords per lane (1 for C=64, 2 for C=128)
    int w = (blockIdx.x * blockDim.x + threadIdx.x) >> 6;
    if (w >= N) return;
    int lane = threadIdx.x & 63;
    int g = lane >> 4;            // edge slot within group (0..3)
    int l = lane & 15;            // segment within row
    int s0 = ptr[w], s1 = ptr[w + 1];
    int deg = s1 - s0;

    floatx2 acc2[2 * NA];
#pragma unroll
    for (int u = 0; u < 2 * NA; ++u) { acc2[u][0] = 0.0f; acc2[u][1] = 0.0f; }

    for (int jb = 0; jb < deg; jb += 64) {
        int rem = min(64, deg - jb);
        int idxreg = (jb + lane < deg) ? srcs[s0 + jb + lane] : 0;
        int fullend = rem & ~15;
        int o0 = 0;
        for (; o0 < fullend; o0 += 16) {     // unchecked full blocks
            uint v[4][NA];
#pragma unroll
            for (int q = 0; q < 4; ++q) {
                int idx = __shfl(idxreg, o0 + q * 4 + g);
                if (NA == 2) {
                    uint2 tt = *(const uint2*)(feat + (size_t)idx * C + l * 8);
                    v[q][0] = tt.x; v[q][1] = tt.y;
                } else {
                    v[q][0] = *(const unsigned*)(feat + (size_t)idx * C + l * 4);
                }
            }
#pragma unroll
            for (int q = 0; q < 4; ++q)
#pragma unroll
                for (int a = 0; a < NA; ++a) {
                    acc2[2 * a + 0] += __builtin_amdgcn_cvt_pk_f32_fp8(v[q][a], false);
                    acc2[2 * a + 1] += __builtin_amdgcn_cvt_pk_f32_fp8(v[q][a], true);
                }
        }
        if (o0 < rem) {                      // checked tail block
            uint v[4][NA];
#pragma unroll
            for (int q = 0; q < 4; ++q) {
                int o = o0 + q * 4 + g;
                int idx = __shfl(idxreg, o);
#pragma unroll
                for (int a = 0; a < NA; ++a) v[q][a] = 0;
                if (o < rem) {
                    if (NA == 2) {
                        uint2 tt = *(const uint2*)(feat + (size_t)idx * C + l * 8);
                        v[q][0] = tt.x; v[q][1] = tt.y;
                    } else {
                        v[q][0] = *(const unsigned*)(feat + (size_t)idx * C + l * 4);
                    }
                }
            }
#pragma unroll
            for (int q = 0; q < 4; ++q)
#pragma unroll
                for (int a = 0; a < NA; ++a) {
                    acc2[2 * a + 0] += __builtin_amdgcn_cvt_pk_f32_fp8(v[q][a], false);
                    acc2[2 * a + 1] += __builtin_amdgcn_cvt_pk_f32_fp8(v[q][a], true);
                }
        }
    }
    // reduce across the 4 edge-slots (lanes differing in bits >= 4)
#pragma unroll
    for (int m = 16; m < 64; m <<= 1) {
#pragma unroll
        for (int u = 0; u < 2 * NA; ++u) {
            acc2[u][0] += __shfl_xor(acc2[u][0], m, 64);
            acc2[u][1] += __shfl_xor(acc2[u][1], m, 64);
        }
    }
    if (g == 0) {
        float inv = (deg > 0) ? 1.0f / (float)deg : 0.0f;
        unsigned short o[4 * NA];
#pragma unroll
        for (int u = 0; u < 2 * NA; ++u) {
            o[2 * u + 0] = f2bf(acc2[u][0] * inv);
            o[2 * u + 1] = f2bf(acc2[u][1] * inv);
        }
        if (NA == 2) *(uint4*)(mean + (size_t)w * C + l * 8) = *(const uint4*)o;
        else *(uint2*)(mean + (size_t)w * C + l * 4) = *(const uint2*)o;
    }
}

// ================= MFMA SAGE GEMM: relu([mean|h] @ [Wn;Ws] + b) =================
// !FUSE_FC: outputs staged through LDS and stored as full coalesced lines
// (direct per-lane 1-2B stores caused 2.5x HBM write amplification — R13 PMC).
// Also emits fp8(e4m3) copy for the next aggregation.
template <int KT, bool FUSE_FC>
__global__ __launch_bounds__(256) void sage_gemm_mfma(const unsigned short* __restrict__ meanb,
                                                      const unsigned short* __restrict__ hb,
                                                      const unsigned short* __restrict__ Bpack,
                                                      const float* __restrict__ bias,
                                                      const float* __restrict__ fcw,
                                                      const float* __restrict__ fcb,
                                                      unsigned short* __restrict__ outb,
                                                      unsigned char* __restrict__ out8,
                                                      float* __restrict__ outf, int N) {
    constexpr int KH = KT / 2;
    constexpr int LDA = KT + 8;
    __shared__ unsigned short As[64 * LDA];
    const int t = threadIdx.x;
    const int row0 = blockIdx.x * 64;

    constexpr int SEGS = KT / 8;
    for (int c = t; c < 64 * SEGS; c += 256) {
        int r = c / SEGS, seg = c % SEGS;
        int rsrc = row0 + r;
        if (rsrc >= N) rsrc = N - 1;
        const unsigned short* srcp = (seg < SEGS / 2)
                                         ? meanb + (size_t)rsrc * KH + seg * 8
                                         : hb + (size_t)rsrc * KH + (seg - SEGS / 2) * 8;
        *(uint4*)&As[r * LDA + seg * 8] = *(const uint4*)srcp;
    }
    __syncthreads();

    const int lane = t & 63;
    const int wave = t >> 6;
    const int quad = lane >> 4;
    const int lo = lane & 15;

    floatx4 acc[8];
#pragma unroll
    for (int i = 0; i < 8; ++i)
#pragma unroll
        for (int r = 0; r < 4; ++r) acc[i][r] = 0.0f;

    const unsigned short* abase = &As[(wave * 16 + lo) * LDA + quad * 8];
#pragma unroll
    for (int s = 0; s < KT / 32; ++s) {
        short8 a = *(const short8*)(abase + s * 32);
        const short8* bp = (const short8*)Bpack + (size_t)(s * 8) * 64 + lane;
#pragma unroll
        for (int tt = 0; tt < 8; ++tt) {
            short8 b = bp[tt * 64];
            acc[tt] = __builtin_amdgcn_mfma_f32_16x16x32_bf16(a, b, acc[tt], 0, 0, 0);
        }
    }

    if (!FUSE_FC) {
        // ---- phase A: stage bf16 rows in LDS, stream out full 256B lines ----
        __syncthreads();  // all As (A-tile) reads complete before reuse
#pragma unroll
        for (int tt = 0; tt < 8; ++tt) {
            int col = tt * 16 + lo;
            float bv = bias[col];
#pragma unroll
            for (int r = 0; r < 4; ++r) {
                int rl = wave * 16 + quad * 4 + r;
                As[rl * LDA + col] = f2bf(fmaxf(acc[tt][r] + bv, 0.0f));
            }
        }
        __syncthreads();
        for (int i = t; i < 64 * (HID / 8); i += 256) {  // 16 threads/row, uint4 each
            int r = i >> 4, ch = i & 15;
            int row = row0 + r;
            if (row < N)
                *(uint4*)(outb + (size_t)row * HID + ch * 8) = *(const uint4*)&As[r * LDA + ch * 8];
        }
        // ---- phase B: recompute from live acc, stage fp8 rows, stream 128B lines ----
        __syncthreads();
        unsigned char* As8 = (unsigned char*)As;
#pragma unroll
        for (int tt = 0; tt < 8; ++tt) {
            int col = tt * 16 + lo;
            float bv = bias[col];
#pragma unroll
            for (int r = 0; r < 4; ++r) {
                int rl = wave * 16 + quad * 4 + r;
                float v = fmaxf(acc[tt][r] + bv, 0.0f);
                int p8 = __builtin_amdgcn_cvt_pk_fp8_f32(v, v, 0, false);
                As8[rl * (LDA * 2) + col] = (unsigned char)(p8 & 0xff);
            }
        }
        __syncthreads();
        for (int i = t; i < 64 * (HID / 16); i += 256) {  // 8 threads/row, uint4 each
            int r = i >> 3, ch = i & 7;
            int row = row0 + r;
            if (row < N)
                *(uint4*)(out8 + (size_t)row * HID + ch * 16) =
                    *(const uint4*)&As8[r * (LDA * 2) + ch * 16];
        }
    } else {
        float o0[4] = {}, o1[4] = {};
#pragma unroll
        for (int tt = 0; tt < 8; ++tt) {
            int col = tt * 16 + lo;
            float bv = bias[col];
            float w0 = fcw[col * 2 + 0];
            float w1 = fcw[col * 2 + 1];
#pragma unroll
            for (int r = 0; r < 4; ++r) {
                float v = fmaxf(acc[tt][r] + bv, 0.0f);
                o0[r] += v * w0;
                o1[r] += v * w1;
            }
        }
#pragma unroll
        for (int r = 0; r < 4; ++r) {
#pragma unroll
            for (int m = 8; m >= 1; m >>= 1) {
                o0[r] += __shfl_xor(o0[r], m, 16);
                o1[r] += __shfl_xor(o1[r], m, 16);
            }
        }
        if (lo == 0) {
#pragma unroll
            for (int r = 0; r < 4; ++r) {
                int row = row0 + wave * 16 + quad * 4 + r;
                if (row < N) {
                    outf[(size_t)row * 2 + 0] = o0[r] + fcb[0];
                    outf[(size_t)row * 2 + 1] = o1[r] + fcb[1];
                }
            }
        }
    }
}

extern "C" void kernel_launch(void* const* d_in, const int* in_sizes, int n_in,
                              void* d_out, int out_size, void* d_ws, size_t ws_size,
                              hipStream_t stream) {
    const float* x   = (const float*)d_in[0];
    const int*   ei  = (const int*)d_in[1];
    const float* Wn0 = (const float*)d_in[2];
    const float* Ws0 = (const float*)d_in[3];
    const float* b0  = (const float*)d_in[4];
    const float* Wn1 = (const float*)d_in[5];
    const float* Ws1 = (const float*)d_in[6];
    const float* b1  = (const float*)d_in[7];
    const float* fcw = (const float*)d_in[8];
    const float* fcb = (const float*)d_in[9];
    float* out = (float*)d_out;

    const int E = in_sizes[1] / 2;
    const int* src = ei;
    const int* dst = ei + E;
    const int N = N_NODES;
    const int chunk = (E + NCB - 1) / NCB;

    // workspace layout
    char* ws = (char*)d_ws;
    size_t off = 0;
    int* table  = (int*)(ws + off); off += (size_t)NBUCK * NCB * 4;
    int* tot    = (int*)(ws + off); off += 4096;
    int* bstart = (int*)(ws + off); off += 4096;
    int* scan_done = (int*)(ws + off); off += 256;
    int* ptr    = (int*)(ws + off); off += (size_t)(N + 1) * 4 + 60; off &= ~(size_t)63;
    unsigned* binned = (unsigned*)(ws + off); off += (size_t)E * 4;
    int* sorted = (int*)(ws + off); off += (size_t)E * 4;
    off = (off + 255) & ~(size_t)255;
    unsigned short* x_bf   = (unsigned short*)(ws + off); off += (size_t)N * IN_CH * 2;
    unsigned short* mean0  = (unsigned short*)(ws + off); off += (size_t)N * IN_CH * 2;
    unsigned short* h1_bf  = (unsigned short*)(ws + off); off += (size_t)N * HID * 2;
    unsigned short* mean1  = (unsigned short*)(ws + off); off += (size_t)N * HID * 2;
    unsigned char*  h1_f8  = (unsigned char*)(ws + off);  off += (size_t)N * HID;
    unsigned char*  x_f8   = (unsigned char*)(ws + off);  off += (size_t)N * IN_CH;
    off = (off + 255) & ~(size_t)255;
    unsigned short* Bpack0 = (unsigned short*)(ws + off); off += (size_t)(2 * IN_CH / 32) * 8 * 64 * 8 * 2;
    unsigned short* Bpack1 = (unsigned short*)(ws + off); off += (size_t)(2 * HID / 32) * 8 * 64 * 8 * 2;

    // ---- CSR build + prep ----
    {
        int n4 = N * IN_CH / 4;
        int nblk = NCB + 24 + (n4 + 255) / 256;
        histprep_kernel<<<nblk, 256, 0, stream>>>(dst, table, E, chunk, x, x_bf, x_f8,
                                                  Wn0, Ws0, Bpack0, Wn1, Ws1, Bpack1,
                                                  scan_done, n4);
    }
    scan12_kernel<<<NBUCK, 256, 0, stream>>>(table, tot, bstart, ptr, scan_done, E);
    bin_kernel<<<NCB, 256, 0, stream>>>(src, dst, table, bstart, binned, E, chunk);
    place_kernel<<<NBUCK, 256, 0, stream>>>(binned, bstart, ptr, sorted, N);

    // ---- layer 0 (fp8 aggregation) ----
    gather_mean_f8<IN_CH><<<(N * 64 + 255) / 256, 256, 0, stream>>>(ptr, sorted, x_f8, mean0, N);
    sage_gemm_mfma<2 * IN_CH, false><<<(N + 63) / 64, 256, 0, stream>>>(
        mean0, x_bf, Bpack0, b0, nullptr, nullptr, h1_bf, h1_f8, nullptr, N);

    // ---- layer 1 (fp8 aggregation) + fused fc ----
    gather_mean_f8<HID><<<(N * 64 + 255) / 256, 256, 0, stream>>>(ptr, sorted, h1_f8, mean1, N);
    sage_gemm_mfma<2 * HID, true><<<(N + 63) / 64, 256, 0, stream>>>(
        mean1, h1_bf, Bpack1, b1, fcw, fcb, nullptr, nullptr, out, N);
}

// Round 16
// 253.494 us; speedup vs baseline: 1.1324x; 1.0015x over previous
//
#include <hip/hip_runtime.h>

#define N_NODES 100000
#define IN_CH 64
#define HID 128
#define NBUCK ((N_NODES + 511) >> 9)   // 196 coarse buckets of 512 nodes
#define NCB 256                        // edge-chunk blocks for hist/bin

typedef short short8 __attribute__((ext_vector_type(8)));
typedef float floatx4 __attribute__((ext_vector_type(4)));
typedef float floatx2 __attribute__((ext_vector_type(2)));

__device__ __forceinline__ unsigned short f2bf(float f) {
    unsigned u = __builtin_bit_cast(unsigned, f);
    u += 0x7fffu + ((u >> 16) & 1u);  // RNE
    return (unsigned short)(u >> 16);
}

// ========= fused hist + prep (bf16/fp8 converts of x + weight packs) =========
template <int K>
__device__ __forceinline__ void pack_dev(const float* __restrict__ Wn,
                                         const float* __restrict__ Ws,
                                         unsigned short* __restrict__ Bpack, int idx) {
    int s = idx >> 9;
    int rem = idx & 511;
    int t = rem >> 6;
    int lane = rem & 63;
    int quad = lane >> 4;
    int n = t * 16 + (lane & 15);
    unsigned short v[8];
#pragma unroll
    for (int j = 0; j < 8; ++j) {
        int k = s * 32 + quad * 8 + j;
        float w = (k < K) ? Wn[(size_t)k * HID + n] : Ws[(size_t)(k - K) * HID + n];
        v[j] = f2bf(w);
    }
    *(short8*)(Bpack + (size_t)idx * 8) = *(short8*)v;
}

// blocks [0,NCB): dst histogram; [NCB,NCB+8): pack0; [NCB+8,NCB+24): pack1; rest: x convert
__global__ __launch_bounds__(256) void histprep_kernel(const int* __restrict__ dst,
                                                       int* __restrict__ table, int E, int chunk,
                                                       const float* __restrict__ x,
                                                       unsigned short* __restrict__ x_bf,
                                                       unsigned char* __restrict__ x_f8,
                                                       const float* __restrict__ Wn0,
                                                       const float* __restrict__ Ws0,
                                                       unsigned short* __restrict__ Bpack0,
                                                       const float* __restrict__ Wn1,
                                                       const float* __restrict__ Ws1,
                                                       unsigned short* __restrict__ Bpack1,
                                                       int* __restrict__ scan_done, int n4) {
    int b = blockIdx.x;
    if (b < NCB) {
        if (b == 0 && threadIdx.x == 0) *scan_done = 0;  // init for scan12's last-block pattern
        __shared__ int h[NBUCK];
        for (int i = threadIdx.x; i < NBUCK; i += 256) h[i] = 0;
        __syncthreads();
        int e0 = b * chunk;
        int e1 = min(E, e0 + chunk);
        for (int e = e0 + threadIdx.x; e < e1; e += 256) atomicAdd(&h[dst[e] >> 9], 1);
        __syncthreads();
        for (int i = threadIdx.x; i < NBUCK; i += 256) table[i * NCB + b] = h[i];
    } else if (b < NCB + 8) {
        pack_dev<IN_CH>(Wn0, Ws0, Bpack0, (b - NCB) * 256 + threadIdx.x);
    } else if (b < NCB + 24) {
        pack_dev<HID>(Wn1, Ws1, Bpack1, (b - NCB - 8) * 256 + threadIdx.x);
    } else {
        int i = (b - NCB - 24) * 256 + threadIdx.x;
        if (i < n4) {
            float4 v = ((const float4*)x)[i];
            ushort4 o;
            o.x = f2bf(v.x); o.y = f2bf(v.y); o.z = f2bf(v.z); o.w = f2bf(v.w);
            ((ushort4*)x_bf)[i] = o;
            int p8 = __builtin_amdgcn_cvt_pk_fp8_f32(v.x, v.y, 0, false);
            p8 = __builtin_amdgcn_cvt_pk_fp8_f32(v.z, v.w, p8, true);
            ((unsigned*)x_f8)[i] = (unsigned)p8;
        }
    }
}

// ===== fused scan: per-bucket scan over block counts (scanb1) + last-done block
// ===== performs the bucket-start scan (scanb2). Device-scope atomics for tot.
__global__ __launch_bounds__(256) void scan12_kernel(int* __restrict__ table,
                                                     int* __restrict__ tot,
                                                     int* __restrict__ bstart,
                                                     int* __restrict__ ptr,
                                                     int* __restrict__ scan_done, int E) {
    __shared__ int s[NCB];
    __shared__ int lastflag;
    int b = blockIdx.x, t = threadIdx.x;
    int c = table[b * NCB + t];
    s[t] = c;
    __syncthreads();
#pragma unroll
    for (int off = 1; off < NCB; off <<= 1) {
        int v = (t >= off) ? s[t - off] : 0;
        __syncthreads();
        s[t] += v;
        __syncthreads();
    }
    table[b * NCB + t] = s[t] - c;
    if (t == NCB - 1) {
        __hip_atomic_store(&tot[b], s[t], __ATOMIC_RELAXED, __HIP_MEMORY_SCOPE_AGENT);
        int prev = __hip_atomic_fetch_add(scan_done, 1, __ATOMIC_ACQ_REL, __HIP_MEMORY_SCOPE_AGENT);
        lastflag = (prev == NBUCK - 1);
    }
    __syncthreads();
    if (!lastflag) return;
    // this block is the last to finish scanb1 — do scanb2 (bucket-start scan)
    int v = (t < NBUCK) ? __hip_atomic_load(&tot[t], __ATOMIC_RELAXED, __HIP_MEMORY_SCOPE_AGENT) : 0;
    s[t] = v;
    __syncthreads();
#pragma unroll
    for (int off = 1; off < 256; off <<= 1) {
        int u = (t >= off) ? s[t - off] : 0;
        __syncthreads();
        s[t] += u;
        __syncthreads();
    }
    if (t < NBUCK) bstart[t] = s[t] - v;
    if (t == 0) {
        bstart[NBUCK] = E;
        ptr[N_NODES] = E;
    }
}

__global__ __launch_bounds__(256) void bin_kernel(const int* __restrict__ src,
                                                  const int* __restrict__ dst,
                                                  const int* __restrict__ table,
                                                  const int* __restrict__ bstart,
                                                  unsigned* __restrict__ binned, int E, int chunk) {
    __shared__ int cur[NBUCK];
    int blk = blockIdx.x;
    for (int i = threadIdx.x; i < NBUCK; i += 256) cur[i] = bstart[i] + table[i * NCB + blk];
    __syncthreads();
    int e0 = blk * chunk;
    int e1 = min(E, e0 + chunk);
    for (int e = e0 + threadIdx.x; e < e1; e += 256) {
        int d = dst[e];
        int b = d >> 9;
        int pos = atomicAdd(&cur[b], 1);  // LDS atomic
        binned[pos] = (unsigned)src[e] | ((unsigned)(d & 511) << 17);
    }
}

__global__ __launch_bounds__(256) void place_kernel(const unsigned* __restrict__ binned,
                                                    const int* __restrict__ bstart,
                                                    int* __restrict__ ptr,
                                                    int* __restrict__ sorted, int N) {
    __shared__ int deg[512];
    __shared__ int cur[512];
    __shared__ int ssum[256];
    int b = blockIdx.x, t = threadIdx.x;
    int start = bstart[b], end = bstart[b + 1];
    deg[t] = 0;
    deg[t + 256] = 0;
    __syncthreads();
    for (int i = start + t; i < end; i += 256) atomicAdd(&deg[binned[i] >> 17], 1);
    __syncthreads();
    int a = deg[2 * t], c = deg[2 * t + 1];
    int s2 = a + c;
    ssum[t] = s2;
    __syncthreads();
#pragma unroll
    for (int off = 1; off < 256; off <<= 1) {
        int u = (t >= off) ? ssum[t - off] : 0;
        __syncthreads();
        ssum[t] += u;
        __syncthreads();
    }
    int excl2 = ssum[t] - s2;
    cur[2 * t] = excl2;
    cur[2 * t + 1] = excl2 + a;
    int n0 = b * 512 + 2 * t;
    if (n0 < N) ptr[n0] = start + excl2;
    if (n0 + 1 < N) ptr[n0 + 1] = start + excl2 + a;
    __syncthreads();
    for (int i = start + t; i < end; i += 256) {
        unsigned p = binned[i];
        int dl = p >> 17;
        int pos = start + atomicAdd(&cur[dl], 1);  // LDS atomic
        sorted[pos] = (int)(p & 0x1FFFF);
    }
}

// ================= gather + mean (fp8 rows, fp32 accumulate, bf16 out) =================
// 16 lanes/row, NA = C/64 dwords/lane; G = 4 edges/slot, STEP = 16 — matches
// deg~Poisson(16). UNCHECKED full blocks + one checked tail; no branches inside
// the load batch (R10 lesson: branching there destroys memory-level parallelism).
template <int C>
__global__ __launch_bounds__(256) void gather_mean_f8(const int* __restrict__ ptr,
                                                      const int* __restrict__ srcs,
                                                      const unsigned char* __restrict__ feat,
                                                      unsigned short* __restrict__ mean, int N) {
    constexpr int NA = C / 64;    // dwords per lane (1 for C=64, 2 for C=128)
    int w = (blockIdx.x * blockDim.x + threadIdx.x) >> 6;
    if (w >= N) return;
    int lane = threadIdx.x & 63;
    int g = lane >> 4;            // edge slot within group (0..3)
    int l = lane & 15;            // segment within row
    int s0 = ptr[w], s1 = ptr[w + 1];
    int deg = s1 - s0;

    floatx2 acc2[2 * NA];
#pragma unroll
    for (int u = 0; u < 2 * NA; ++u) { acc2[u][0] = 0.0f; acc2[u][1] = 0.0f; }

    for (int jb = 0; jb < deg; jb += 64) {
        int rem = min(64, deg - jb);
        int idxreg = (jb + lane < deg) ? srcs[s0 + jb + lane] : 0;
        int fullend = rem & ~15;
        int o0 = 0;
        for (; o0 < fullend; o0 += 16) {     // unchecked full blocks
            uint v[4][NA];
#pragma unroll
            for (int q = 0; q < 4; ++q) {
                int idx = __shfl(idxreg, o0 + q * 4 + g);
                if (NA == 2) {
                    uint2 tt = *(const uint2*)(feat + (size_t)idx * C + l * 8);
                    v[q][0] = tt.x; v[q][1] = tt.y;
                } else {
                    v[q][0] = *(const unsigned*)(feat + (size_t)idx * C + l * 4);
                }
            }
#pragma unroll
            for (int q = 0; q < 4; ++q)
#pragma unroll
                for (int a = 0; a < NA; ++a) {
                    acc2[2 * a + 0] += __builtin_amdgcn_cvt_pk_f32_fp8(v[q][a], false);
                    acc2[2 * a + 1] += __builtin_amdgcn_cvt_pk_f32_fp8(v[q][a], true);
                }
        }
        if (o0 < rem) {                      // checked tail block
            uint v[4][NA];
#pragma unroll
            for (int q = 0; q < 4; ++q) {
                int o = o0 + q * 4 + g;
                int idx = __shfl(idxreg, o);
#pragma unroll
                for (int a = 0; a < NA; ++a) v[q][a] = 0;
                if (o < rem) {
                    if (NA == 2) {
                        uint2 tt = *(const uint2*)(feat + (size_t)idx * C + l * 8);
                        v[q][0] = tt.x; v[q][1] = tt.y;
                    } else {
                        v[q][0] = *(const unsigned*)(feat + (size_t)idx * C + l * 4);
                    }
                }
            }
#pragma unroll
            for (int q = 0; q < 4; ++q)
#pragma unroll
                for (int a = 0; a < NA; ++a) {
                    acc2[2 * a + 0] += __builtin_amdgcn_cvt_pk_f32_fp8(v[q][a], false);
                    acc2[2 * a + 1] += __builtin_amdgcn_cvt_pk_f32_fp8(v[q][a], true);
                }
        }
    }
    // reduce across the 4 edge-slots (lanes differing in bits >= 4)
#pragma unroll
    for (int m = 16; m < 64; m <<= 1) {
#pragma unroll
        for (int u = 0; u < 2 * NA; ++u) {
            acc2[u][0] += __shfl_xor(acc2[u][0], m, 64);
            acc2[u][1] += __shfl_xor(acc2[u][1], m, 64);
        }
    }
    if (g == 0) {
        float inv = (deg > 0) ? 1.0f / (float)deg : 0.0f;
        unsigned short o[4 * NA];
#pragma unroll
        for (int u = 0; u < 2 * NA; ++u) {
            o[2 * u + 0] = f2bf(acc2[u][0] * inv);
            o[2 * u + 1] = f2bf(acc2[u][1] * inv);
        }
        if (NA == 2) *(uint4*)(mean + (size_t)w * C + l * 8) = *(const uint4*)o;
        else *(uint2*)(mean + (size_t)w * C + l * 4) = *(const uint2*)o;
    }
}

// ================= MFMA SAGE GEMM: relu([mean|h] @ [Wn;Ws] + b) =================
// Self (h) half stays bf16 — R15 PMC lesson: fp8 on the un-averaged self path
// quadruples absmax (0.031->0.117, fails). fp8 only where a mean follows.
// !FUSE_FC: outputs staged through LDS and stored as full coalesced lines
// (direct per-lane 1-2B stores caused 2.5x HBM write amplification — R13 PMC).
template <int KT, bool FUSE_FC>
__global__ __launch_bounds__(256) void sage_gemm_mfma(const unsigned short* __restrict__ meanb,
                                                      const unsigned short* __restrict__ hb,
                                                      const unsigned short* __restrict__ Bpack,
                                                      const float* __restrict__ bias,
                                                      const float* __restrict__ fcw,
                                                      const float* __restrict__ fcb,
                                                      unsigned short* __restrict__ outb,
                                                      unsigned char* __restrict__ out8,
                                                      float* __restrict__ outf, int N) {
    constexpr int KH = KT / 2;
    constexpr int LDA = KT + 8;
    __shared__ unsigned short As[64 * LDA];
    const int t = threadIdx.x;
    const int row0 = blockIdx.x * 64;

    constexpr int SEGS = KT / 8;
    for (int c = t; c < 64 * SEGS; c += 256) {
        int r = c / SEGS, seg = c % SEGS;
        int rsrc = row0 + r;
        if (rsrc >= N) rsrc = N - 1;
        const unsigned short* srcp = (seg < SEGS / 2)
                                         ? meanb + (size_t)rsrc * KH + seg * 8
                                         : hb + (size_t)rsrc * KH + (seg - SEGS / 2) * 8;
        *(uint4*)&As[r * LDA + seg * 8] = *(const uint4*)srcp;
    }
    __syncthreads();

    const int lane = t & 63;
    const int wave = t >> 6;
    const int quad = lane >> 4;
    const int lo = lane & 15;

    floatx4 acc[8];
#pragma unroll
    for (int i = 0; i < 8; ++i)
#pragma unroll
        for (int r = 0; r < 4; ++r) acc[i][r] = 0.0f;

    const unsigned short* abase = &As[(wave * 16 + lo) * LDA + quad * 8];
#pragma unroll
    for (int s = 0; s < KT / 32; ++s) {
        short8 a = *(const short8*)(abase + s * 32);
        const short8* bp = (const short8*)Bpack + (size_t)(s * 8) * 64 + lane;
#pragma unroll
        for (int tt = 0; tt < 8; ++tt) {
            short8 b = bp[tt * 64];
            acc[tt] = __builtin_amdgcn_mfma_f32_16x16x32_bf16(a, b, acc[tt], 0, 0, 0);
        }
    }

    if (!FUSE_FC) {
        // ---- phase A: stage bf16 rows in LDS, stream out full 256B lines ----
        __syncthreads();  // all As (A-tile) reads complete before reuse
#pragma unroll
        for (int tt = 0; tt < 8; ++tt) {
            int col = tt * 16 + lo;
            float bv = bias[col];
#pragma unroll
            for (int r = 0; r < 4; ++r) {
                int rl = wave * 16 + quad * 4 + r;
                As[rl * LDA + col] = f2bf(fmaxf(acc[tt][r] + bv, 0.0f));
            }
        }
        __syncthreads();
        for (int i = t; i < 64 * (HID / 8); i += 256) {  // 16 threads/row, uint4 each
            int r = i >> 4, ch = i & 15;
            int row = row0 + r;
            if (row < N)
                *(uint4*)(outb + (size_t)row * HID + ch * 8) = *(const uint4*)&As[r * LDA + ch * 8];
        }
        // ---- phase B: recompute from live acc, stage fp8 rows, stream 128B lines ----
        __syncthreads();
        unsigned char* As8 = (unsigned char*)As;
#pragma unroll
        for (int tt = 0; tt < 8; ++tt) {
            int col = tt * 16 + lo;
            float bv = bias[col];
#pragma unroll
            for (int r = 0; r < 4; ++r) {
                int rl = wave * 16 + quad * 4 + r;
                float v = fmaxf(acc[tt][r] + bv, 0.0f);
                int p8 = __builtin_amdgcn_cvt_pk_fp8_f32(v, v, 0, false);
                As8[rl * (LDA * 2) + col] = (unsigned char)(p8 & 0xff);
            }
        }
        __syncthreads();
        for (int i = t; i < 64 * (HID / 16); i += 256) {  // 8 threads/row, uint4 each
            int r = i >> 3, ch = i & 7;
            int row = row0 + r;
            if (row < N)
                *(uint4*)(out8 + (size_t)row * HID + ch * 16) =
                    *(const uint4*)&As8[r * (LDA * 2) + ch * 16];
        }
    } else {
        float o0[4] = {}, o1[4] = {};
#pragma unroll
        for (int tt = 0; tt < 8; ++tt) {
            int col = tt * 16 + lo;
            float bv = bias[col];
            float w0 = fcw[col * 2 + 0];
            float w1 = fcw[col * 2 + 1];
#pragma unroll
            for (int r = 0; r < 4; ++r) {
                float v = fmaxf(acc[tt][r] + bv, 0.0f);
                o0[r] += v * w0;
                o1[r] += v * w1;
            }
        }
#pragma unroll
        for (int r = 0; r < 4; ++r) {
#pragma unroll
            for (int m = 8; m >= 1; m >>= 1) {
                o0[r] += __shfl_xor(o0[r], m, 16);
                o1[r] += __shfl_xor(o1[r], m, 16);
            }
        }
        if (lo == 0) {
#pragma unroll
            for (int r = 0; r < 4; ++r) {
                int row = row0 + wave * 16 + quad * 4 + r;
                if (row < N) {
                    outf[(size_t)row * 2 + 0] = o0[r] + fcb[0];
                    outf[(size_t)row * 2 + 1] = o1[r] + fcb[1];
                }
            }
        }
    }
}

extern "C" void kernel_launch(void* const* d_in, const int* in_sizes, int n_in,
                              void* d_out, int out_size, void* d_ws, size_t ws_size,
                              hipStream_t stream) {
    const float* x   = (const float*)d_in[0];
    const int*   ei  = (const int*)d_in[1];
    const float* Wn0 = (const float*)d_in[2];
    const float* Ws0 = (const float*)d_in[3];
    const float* b0  = (const float*)d_in[4];
    const float* Wn1 = (const float*)d_in[5];
    const float* Ws1 = (const float*)d_in[6];
    const float* b1  = (const float*)d_in[7];
    const float* fcw = (const float*)d_in[8];
    const float* fcb = (const float*)d_in[9];
    float* out = (float*)d_out;

    const int E = in_sizes[1] / 2;
    const int* src = ei;
    const int* dst = ei + E;
    const int N = N_NODES;
    const int chunk = (E + NCB - 1) / NCB;

    // workspace layout
    char* ws = (char*)d_ws;
    size_t off = 0;
    int* table  = (int*)(ws + off); off += (size_t)NBUCK * NCB * 4;
    int* tot    = (int*)(ws + off); off += 4096;
    int* bstart = (int*)(ws + off); off += 4096;
    int* scan_done = (int*)(ws + off); off += 256;
    int* ptr    = (int*)(ws + off); off += (size_t)(N + 1) * 4 + 60; off &= ~(size_t)63;
    unsigned* binned = (unsigned*)(ws + off); off += (size_t)E * 4;
    int* sorted = (int*)(ws + off); off += (size_t)E * 4;
    off = (off + 255) & ~(size_t)255;
    unsigned short* x_bf   = (unsigned short*)(ws + off); off += (size_t)N * IN_CH * 2;
    unsigned short* mean0  = (unsigned short*)(ws + off); off += (size_t)N * IN_CH * 2;
    unsigned short* h1_bf  = (unsigned short*)(ws + off); off += (size_t)N * HID * 2;
    unsigned short* mean1  = (unsigned short*)(ws + off); off += (size_t)N * HID * 2;
    unsigned char*  h1_f8  = (unsigned char*)(ws + off);  off += (size_t)N * HID;
    unsigned char*  x_f8   = (unsigned char*)(ws + off);  off += (size_t)N * IN_CH;
    off = (off + 255) & ~(size_t)255;
    unsigned short* Bpack0 = (unsigned short*)(ws + off); off += (size_t)(2 * IN_CH / 32) * 8 * 64 * 8 * 2;
    unsigned short* Bpack1 = (unsigned short*)(ws + off); off += (size_t)(2 * HID / 32) * 8 * 64 * 8 * 2;

    // ---- CSR build + prep ----
    {
        int n4 = N * IN_CH / 4;
        int nblk = NCB + 24 + (n4 + 255) / 256;
        histprep_kernel<<<nblk, 256, 0, stream>>>(dst, table, E, chunk, x, x_bf, x_f8,
                                                  Wn0, Ws0, Bpack0, Wn1, Ws1, Bpack1,
                                                  scan_done, n4);
    }
    scan12_kernel<<<NBUCK, 256, 0, stream>>>(table, tot, bstart, ptr, scan_done, E);
    bin_kernel<<<NCB, 256, 0, stream>>>(src, dst, table, bstart, binned, E, chunk);
    place_kernel<<<NBUCK, 256, 0, stream>>>(binned, bstart, ptr, sorted, N);

    // ---- layer 0 (fp8 aggregation, bf16 self) ----
    gather_mean_f8<IN_CH><<<(N * 64 + 255) / 256, 256, 0, stream>>>(ptr, sorted, x_f8, mean0, N);
    sage_gemm_mfma<2 * IN_CH, false><<<(N + 63) / 64, 256, 0, stream>>>(
        mean0, x_bf, Bpack0, b0, nullptr, nullptr, h1_bf, h1_f8, nullptr, N);

    // ---- layer 1 (fp8 aggregation, bf16 self) + fused fc ----
    gather_mean_f8<HID><<<(N * 64 + 255) / 256, 256, 0, stream>>>(ptr, sorted, h1_f8, mean1, N);
    sage_gemm_mfma<2 * HID, true><<<(N + 63) / 64, 256, 0, stream>>>(
        mean1, h1_bf, Bpack1, b1, fcw, fcb, nullptr, nullptr, out, N);
}